// Round 7
// baseline (138.321 us; speedup 1.0000x reference)
//
#include <hip/hip_runtime.h>
#include <math.h>

// Problem constants (fixed by the reference setup_inputs).
constexpr int B = 8, N = 16384, P = 512, D = 64;
constexpr int NSPLIT   = 16;              // N-splits (grid.x)
constexpr int ROWS_PB  = N / NSPLIT;      // 1024 rows per block
constexpr int CHUNK    = 128;             // rows per LDS chunk
constexpr int NCHUNK   = ROWS_PB / CHUNK; // 8
constexpr int TPB      = 128;             // protos per block (grid.y = P/TPB = 4)

typedef __attribute__((ext_vector_type(8))) _Float16 f16x8;  // 8 f16 = 4 VGPR
typedef __attribute__((ext_vector_type(4))) float f32x4;
typedef __attribute__((ext_vector_type(4))) int   i32x4;
using u32 = unsigned int;
using u64 = unsigned long long;

// LDS map (bytes):
//   xbuf0 : [0,     32768)   128 rows x 256B (2 f16 planes H|L, XOR-swizzled)
//   xbuf1 : [32768, 65536)
//   x2s   : [65536, 66560)   2 x 128 f32
//   p2s   : [69632, 70144)   128 f32
//   p-temp (phase P only): [0, 34816) = 128 rows x 272B stride (overlaps xbuf0/1)
constexpr int X2S   = 65536;
constexpr int P2S   = 69632;
constexpr int SMEMB = 70144;   // 2 blocks/CU: 2x70144 = 140288 <= 163840

// f32 -> (f16 hi, f16 lo) exact-residual split; pack pairs of values.
__device__ __forceinline__ void cvt2(float a, float b, u32& hw, u32& lw) {
    _Float16 ha = (_Float16)a, hb = (_Float16)b;
    float ra = a - (float)ha, rb = b - (float)hb;     // exact (Sterbenz)
    _Float16 la = (_Float16)ra, lb = (_Float16)rb;
    hw = (u32)__builtin_bit_cast(unsigned short, ha) |
         ((u32)__builtin_bit_cast(unsigned short, hb) << 16);
    lw = (u32)__builtin_bit_cast(unsigned short, la) |
         ((u32)__builtin_bit_cast(unsigned short, lb) << 16);
}

__global__ __launch_bounds__(512, 4)   // 4 waves/EU -> 2 blocks/CU, VGPR cap 128
void kmain(const float* __restrict__ x, const float* __restrict__ proto,
           u64* __restrict__ pk) {
    __shared__ __align__(16) char smem[SMEMB];
    const int t  = threadIdx.x;
    const int l  = t & 63;
    const int wv = t >> 6;
    const int wr = wv >> 1, wc = wv & 1;     // wave 4x2 grid: 32 rows x 64 protos each
    const int hi = l >> 4, il = l & 15;
    const int ns = blockIdx.x, pt = blockIdx.y, b = blockIdx.z;
    const int n0  = ns * ROWS_PB;
    const int pt0 = pt * TPB;

    // ---------- Phase P: normalize protos, split to 2 f16 planes in LDS ----------
    if (t < TPB) {
        const float4* pr4 = reinterpret_cast<const float4*>(proto + (size_t)(pt0 + t) * D);
        float a0 = 0.f, a1 = 0.f, a2 = 0.f, a3 = 0.f;
        float4 v[16];
        #pragma unroll
        for (int i = 0; i < 16; ++i) {
            v[i] = pr4[i];
            a0 = fmaf(v[i].x, v[i].x, a0);
            a1 = fmaf(v[i].y, v[i].y, a1);
            a2 = fmaf(v[i].z, v[i].z, a2);
            a3 = fmaf(v[i].w, v[i].w, a3);
        }
        float nrm = sqrtf((a0 + a1) + (a2 + a3));
        float sc  = 1.0f / fmaxf(nrm, 1e-12f);
        char* prow = smem + t * 272;   // p-temp row, stride 272B (bank spread)
        float q0 = 0.f, q1 = 0.f, q2 = 0.f, q3 = 0.f;
        #pragma unroll
        for (int g = 0; g < 8; ++g) {  // 8 k-values per group
            float4 va = v[2 * g], vb = v[2 * g + 1];
            float e[8] = {va.x * sc, va.y * sc, va.z * sc, va.w * sc,
                          vb.x * sc, vb.y * sc, vb.z * sc, vb.w * sc};
            q0 = fmaf(e[0], e[0], fmaf(e[4], e[4], q0));
            q1 = fmaf(e[1], e[1], fmaf(e[5], e[5], q1));
            q2 = fmaf(e[2], e[2], fmaf(e[6], e[6], q2));
            q3 = fmaf(e[3], e[3], fmaf(e[7], e[7], q3));
            u32 H[4], Lo[4];
            #pragma unroll
            for (int jj = 0; jj < 4; ++jj)
                cvt2(e[2 * jj], e[2 * jj + 1], H[jj], Lo[jj]);
            *reinterpret_cast<i32x4*>(prow +       g * 16) = i32x4{(int)H[0], (int)H[1], (int)H[2], (int)H[3]};
            *reinterpret_cast<i32x4*>(prow + 128 + g * 16) = i32x4{(int)Lo[0], (int)Lo[1], (int)Lo[2], (int)Lo[3]};
        }
        *reinterpret_cast<float*>(smem + P2S + t * 4) = (q0 + q1) + (q2 + q3);
    }
    __syncthreads();

    // ---------- Load B-fragments into registers ----------
    // mfma_f32_16x16x32_f16 B layout: lane l -> col = l&15, k = (l>>4)*8 + j
    f16x8 bh[2][4], bl[2][4];
    #pragma unroll
    for (int s = 0; s < 2; ++s)
        #pragma unroll
        for (int ni = 0; ni < 4; ++ni) {
            int row = wc * 64 + ni * 16 + il;       // local proto [0,128)
            int off = s * 64 + hi * 16;             // kk = s*32 + hi*8
            bh[s][ni] = *reinterpret_cast<const f16x8*>(smem + row * 272 + off);
            bl[s][ni] = *reinterpret_cast<const f16x8*>(smem + row * 272 + 128 + off);
        }
    float p2c[4];
    #pragma unroll
    for (int ni = 0; ni < 4; ++ni)
        p2c[ni] = *reinterpret_cast<const float*>(smem + P2S + (wc * 64 + ni * 16 + il) * 4);
    __syncthreads();   // p-temp region now reusable as x buffers

    // per-lane A-frag address pieces (swizzle: off ^ ((row&7)<<4), row&7 == il&7;
    // bits 4-5 folded into alow, bit 6 applied to the s*64 term)
    const int alow  = (hi * 16) ^ ((il & 3) << 4);
    const int abit6 = (il & 4) << 4;
    int rowoff[2];
    #pragma unroll
    for (int mi = 0; mi < 2; ++mi)
        rowoff[mi] = (wr * 32 + mi * 16 + il) * 256 + alow;

    const float* gx = x + ((size_t)b * N + n0) * D + t * 16;  // row t>>2, quarter t&3

    // ---- staging: load 16 f32, split to 2 f16 planes, swizzled ds_write; fold x2 ----
    auto stage = [&](int c, int buf) {
        const float4* src = reinterpret_cast<const float4*>(gx + (size_t)c * CHUNK * D);
        float4 L0 = src[0], L1 = src[1], L2 = src[2], L3 = src[3];
        float vals[16] = {L0.x, L0.y, L0.z, L0.w, L1.x, L1.y, L1.z, L1.w,
                          L2.x, L2.y, L2.z, L2.w, L3.x, L3.y, L3.z, L3.w};
        float s16 = 0.f;
        #pragma unroll
        for (int i = 0; i < 16; ++i) s16 = fmaf(vals[i], vals[i], s16);
        s16 += __shfl_xor(s16, 1);
        s16 += __shfl_xor(s16, 2);
        int row = t >> 2, q = t & 3;
        if (q == 0) *reinterpret_cast<float*>(smem + X2S + buf * 512 + row * 4) = s16;
        char* base = smem + buf * 32768 + row * 256;
        int sw = (row & 7) << 4;
        #pragma unroll
        for (int hf = 0; hf < 2; ++hf) {
            u32 H[4], Lo[4];
            #pragma unroll
            for (int jj = 0; jj < 4; ++jj)
                cvt2(vals[hf * 8 + 2 * jj], vals[hf * 8 + 2 * jj + 1], H[jj], Lo[jj]);
            int ob = (q * 32 + hf * 16) ^ sw;
            *reinterpret_cast<i32x4*>(base +       ob) = i32x4{(int)H[0], (int)H[1], (int)H[2], (int)H[3]};
            *reinterpret_cast<i32x4*>(base + 128 + ob) = i32x4{(int)Lo[0], (int)Lo[1], (int)Lo[2], (int)Lo[3]};
        }
    };

    stage(0, 0);
    __syncthreads();

    float msq[4]  = {3.4e38f, 3.4e38f, 3.4e38f, 3.4e38f};
    int   midx[4] = {0, 0, 0, 0};

    for (int c = 0; c < NCHUNK; ++c) {
        const int buf = c & 1;
        f32x4 acc[2][4];
        #pragma unroll
        for (int mi = 0; mi < 2; ++mi)
            #pragma unroll
            for (int ni = 0; ni < 4; ++ni) acc[mi][ni] = f32x4{0.f, 0.f, 0.f, 0.f};

        const int bufo = buf * 32768;
        #pragma unroll
        for (int s = 0; s < 2; ++s) {
            f16x8 ah[2], al[2];
            const int offh = (s * 64) ^ abit6;
            #pragma unroll
            for (int mi = 0; mi < 2; ++mi) {
                ah[mi] = *reinterpret_cast<const f16x8*>(smem + bufo + rowoff[mi] + offh);
                al[mi] = *reinterpret_cast<const f16x8*>(smem + bufo + rowoff[mi] + 128 + offh);
            }
            #pragma unroll
            for (int mi = 0; mi < 2; ++mi)
                #pragma unroll
                for (int ni = 0; ni < 4; ++ni) {
                    acc[mi][ni] = __builtin_amdgcn_mfma_f32_16x16x32_f16(
                        ah[mi], bh[s][ni], acc[mi][ni], 0, 0, 0);
                    acc[mi][ni] = __builtin_amdgcn_mfma_f32_16x16x32_f16(
                        ah[mi], bl[s][ni], acc[mi][ni], 0, 0, 0);
                    acc[mi][ni] = __builtin_amdgcn_mfma_f32_16x16x32_f16(
                        al[mi], bh[s][ni], acc[mi][ni], 0, 0, 0);
                }
        }

        // epilogue: sq = x2 + p2 - 2*dot; strict-< + ascending idx keeps first occurrence
        const float* x2p = reinterpret_cast<const float*>(smem + X2S + buf * 512);
        const int idxb = n0 + c * CHUNK + wr * 32 + hi * 4;
        #pragma unroll
        for (int mi = 0; mi < 2; ++mi) {
            f32x4 xv = *reinterpret_cast<const f32x4*>(x2p + wr * 32 + mi * 16 + hi * 4);
            #pragma unroll
            for (int ni = 0; ni < 4; ++ni) {
                #pragma unroll
                for (int r = 0; r < 4; ++r) {
                    float sq = fmaf(-2.0f, acc[mi][ni][r], xv[r] + p2c[ni]);
                    sq = fmaxf(sq, 0.0f);
                    int idx = idxb + mi * 16 + r;
                    if (sq < msq[ni]) { msq[ni] = sq; midx[ni] = idx; }
                }
            }
        }

        if (c + 1 < NCHUNK) stage(c + 1, buf ^ 1);
        __syncthreads();
    }

    // ---------- reduce: u64 key = (sq_bits<<32)|idx; lower idx wins ties ----------
    u64 key[4];
    #pragma unroll
    for (int ni = 0; ni < 4; ++ni) {
        u64 k = ((u64)__float_as_uint(msq[ni]) << 32) | (u32)midx[ni];
        u64 o = __shfl_xor(k, 16); k = o < k ? o : k;
        o     = __shfl_xor(k, 32); k = o < k ? o : k;
        key[ni] = k;
    }
    u64 k01 = (l & 16) ? key[1] : key[0];
    u64 k23 = (l & 16) ? key[3] : key[2];
    u64 kk  = (l & 32) ? k23 : k01;          // proto_local = wc*64 + l
    u64* xch = reinterpret_cast<u64*>(smem);
    if (wr > 0) xch[(wr - 1) * 128 + wc * 64 + l] = kk;
    __syncthreads();
    if (wr == 0) {
        #pragma unroll
        for (int q = 0; q < 3; ++q) {
            u64 o = xch[q * 128 + wc * 64 + l];
            kk = o < kk ? o : kk;
        }
        pk[(size_t)ns * (B * P) + (size_t)b * P + pt0 + wc * 64 + l] = kk;
    }
}

__global__ void kfin(const u64* __restrict__ pk, float* __restrict__ out) {
    int i = blockIdx.x * 256 + threadIdx.x;
    if (i >= B * P) return;
    u64 m = pk[i];
    #pragma unroll
    for (int s = 1; s < NSPLIT; ++s) {
        u64 c = pk[(size_t)s * (B * P) + i];
        m = c < m ? c : m;
    }
    float sq = __uint_as_float((u32)(m >> 32));
    out[i] = sqrtf(sq + 1e-8f);                              // prototype_dist
    out[B * P + i] = (float)(u32)(m & 0xFFFFFFFFu);          // patches_idcs (as f32)
}

extern "C" void kernel_launch(void* const* d_in, const int* in_sizes, int n_in,
                              void* d_out, int out_size, void* d_ws, size_t ws_size,
                              hipStream_t stream) {
    const float* x     = (const float*)d_in[0];
    const float* proto = (const float*)d_in[1];
    float* out = (float*)d_out;
    u64* pk = (u64*)d_ws;   // NSPLIT * B * P * 8B = 512 KiB

    kmain<<<dim3(NSPLIT, P / TPB, B), dim3(512), 0, stream>>>(x, proto, pk);
    kfin<<<dim3((B * P + 255) / 256), dim3(256), 0, stream>>>(pk, out);
}

// Round 8
// 108.135 us; speedup vs baseline: 1.2791x; 1.2791x over previous
//
#include <hip/hip_runtime.h>
#include <math.h>

// Problem constants (fixed by the reference setup_inputs).
constexpr int B = 8, N = 16384, P = 512, D = 64;
constexpr int NSPLIT   = 32;              // N-splits (grid.x) -> 512 blocks total
constexpr int ROWS_PB  = N / NSPLIT;      // 512 rows per block
constexpr int CHUNK    = 128;             // rows per LDS chunk
constexpr int NCHUNK   = ROWS_PB / CHUNK; // 4
constexpr int TPB      = 256;             // protos per block (grid.y = P/TPB = 2)

typedef __attribute__((ext_vector_type(8))) _Float16 f16x8;  // 8 f16 = 4 VGPR
typedef __attribute__((ext_vector_type(4))) float f32x4;
typedef __attribute__((ext_vector_type(4))) int   i32x4;
using u32 = unsigned int;
using u64 = unsigned long long;

// LDS map (bytes):
//   xbuf0 : [0,     32768)   128 rows x 256B (2 f16 planes H|L, XOR-swizzled)
//   xbuf1 : [32768, 65536)
//   x2s   : [65536, 66560)   2 x 128 f32
//   p2s   : [69632, 70656)   256 f32
//   p-temp (phase P only): [0, 69632) = 256 rows x 272B stride (overlaps xbufs+x2s)
constexpr int X2S   = 65536;
constexpr int P2S   = 69632;
constexpr int SMEMB = 70656;   // 2 blocks/CU: 2x70656 = 141312 <= 163840

// f32 -> (f16 hi, f16 lo) exact-residual split; pack pairs of values.
__device__ __forceinline__ void cvt2(float a, float b, u32& hw, u32& lw) {
    _Float16 ha = (_Float16)a, hb = (_Float16)b;
    float ra = a - (float)ha, rb = b - (float)hb;     // exact
    _Float16 la = (_Float16)ra, lb = (_Float16)rb;
    hw = (u32)__builtin_bit_cast(unsigned short, ha) |
         ((u32)__builtin_bit_cast(unsigned short, hb) << 16);
    lw = (u32)__builtin_bit_cast(unsigned short, la) |
         ((u32)__builtin_bit_cast(unsigned short, lb) << 16);
}

__global__ __launch_bounds__(512, 2)   // NO tighter cap: avoid round-7 spills
void kmain(const float* __restrict__ x, const float* __restrict__ proto,
           u64* __restrict__ pk) {
    __shared__ __align__(16) char smem[SMEMB];
    const int t  = threadIdx.x;
    const int l  = t & 63;
    const int wv = t >> 6;
    const int wr = wv >> 2, wc = wv & 3;     // wave 2x4 grid: 64 rows x 64 protos
    const int hi = l >> 4, il = l & 15;
    const int ns = blockIdx.x, pt = blockIdx.y, b = blockIdx.z;
    const int n0  = ns * ROWS_PB;
    const int pt0 = pt * TPB;

    // ---------- Phase P: normalize protos, split to 2 f16 planes in LDS ----------
    if (t < TPB) {
        const float4* pr4 = reinterpret_cast<const float4*>(proto + (size_t)(pt0 + t) * D);
        float a0 = 0.f, a1 = 0.f, a2 = 0.f, a3 = 0.f;
        float4 v[16];
        #pragma unroll
        for (int i = 0; i < 16; ++i) {
            v[i] = pr4[i];
            a0 = fmaf(v[i].x, v[i].x, a0);
            a1 = fmaf(v[i].y, v[i].y, a1);
            a2 = fmaf(v[i].z, v[i].z, a2);
            a3 = fmaf(v[i].w, v[i].w, a3);
        }
        float nrm = sqrtf((a0 + a1) + (a2 + a3));
        float sc  = 1.0f / fmaxf(nrm, 1e-12f);
        char* prow = smem + t * 272;   // p-temp row, stride 272B (bank spread)
        float q0 = 0.f, q1 = 0.f, q2 = 0.f, q3 = 0.f;
        #pragma unroll
        for (int g = 0; g < 8; ++g) {  // 8 k-values per group
            float4 va = v[2 * g], vb = v[2 * g + 1];
            float e[8] = {va.x * sc, va.y * sc, va.z * sc, va.w * sc,
                          vb.x * sc, vb.y * sc, vb.z * sc, vb.w * sc};
            q0 = fmaf(e[0], e[0], fmaf(e[4], e[4], q0));
            q1 = fmaf(e[1], e[1], fmaf(e[5], e[5], q1));
            q2 = fmaf(e[2], e[2], fmaf(e[6], e[6], q2));
            q3 = fmaf(e[3], e[3], fmaf(e[7], e[7], q3));
            u32 H[4], Lo[4];
            #pragma unroll
            for (int jj = 0; jj < 4; ++jj)
                cvt2(e[2 * jj], e[2 * jj + 1], H[jj], Lo[jj]);
            *reinterpret_cast<i32x4*>(prow +       g * 16) = i32x4{(int)H[0], (int)H[1], (int)H[2], (int)H[3]};
            *reinterpret_cast<i32x4*>(prow + 128 + g * 16) = i32x4{(int)Lo[0], (int)Lo[1], (int)Lo[2], (int)Lo[3]};
        }
        *reinterpret_cast<float*>(smem + P2S + t * 4) = (q0 + q1) + (q2 + q3);
    }
    __syncthreads();

    // ---------- Load B-fragments into registers ----------
    // mfma_f32_16x16x32_f16 B layout: lane l -> col = l&15, k = (l>>4)*8 + j
    f16x8 bh[2][4], bl[2][4];
    #pragma unroll
    for (int s = 0; s < 2; ++s)
        #pragma unroll
        for (int ni = 0; ni < 4; ++ni) {
            int row = wc * 64 + ni * 16 + il;       // local proto
            int off = s * 64 + hi * 16;             // kk = s*32 + hi*8
            bh[s][ni] = *reinterpret_cast<const f16x8*>(smem + row * 272 + off);
            bl[s][ni] = *reinterpret_cast<const f16x8*>(smem + row * 272 + 128 + off);
        }
    float p2c[4];
    #pragma unroll
    for (int ni = 0; ni < 4; ++ni)
        p2c[ni] = *reinterpret_cast<const float*>(smem + P2S + (wc * 64 + ni * 16 + il) * 4);
    __syncthreads();   // p-temp region now reusable as x buffers

    // per-lane A-frag address pieces (swizzle: off ^ ((row&7)<<4), row&7 == il&7;
    // bits 4-5 folded into alow, bit 6 applied to the s*64 term)
    const int alow  = (hi * 16) ^ ((il & 3) << 4);
    const int abit6 = (il & 4) << 4;
    int rowoff[4];
    #pragma unroll
    for (int mi = 0; mi < 4; ++mi)
        rowoff[mi] = (wr * 64 + mi * 16 + il) * 256 + alow;

    const float* gx = x + ((size_t)b * N + n0) * D + t * 16;  // row t>>2, quarter t&3

    // ---- staging: 16 f32 -> 2 f16 planes, swizzled ds_write; fold x2 ----
    auto stage = [&](const float4* L, int buf) {
        float vals[16] = {L[0].x, L[0].y, L[0].z, L[0].w, L[1].x, L[1].y, L[1].z, L[1].w,
                          L[2].x, L[2].y, L[2].z, L[2].w, L[3].x, L[3].y, L[3].z, L[3].w};
        float s16 = 0.f;
        #pragma unroll
        for (int i = 0; i < 16; ++i) s16 = fmaf(vals[i], vals[i], s16);
        s16 += __shfl_xor(s16, 1);
        s16 += __shfl_xor(s16, 2);
        int row = t >> 2, q = t & 3;
        if (q == 0) *reinterpret_cast<float*>(smem + X2S + buf * 512 + row * 4) = s16;
        char* base = smem + buf * 32768 + row * 256;
        int sw = (row & 7) << 4;
        #pragma unroll
        for (int hf = 0; hf < 2; ++hf) {
            u32 H[4], Lo[4];
            #pragma unroll
            for (int jj = 0; jj < 4; ++jj)
                cvt2(vals[hf * 8 + 2 * jj], vals[hf * 8 + 2 * jj + 1], H[jj], Lo[jj]);
            int ob = (q * 32 + hf * 16) ^ sw;
            *reinterpret_cast<i32x4*>(base +       ob) = i32x4{(int)H[0], (int)H[1], (int)H[2], (int)H[3]};
            *reinterpret_cast<i32x4*>(base + 128 + ob) = i32x4{(int)Lo[0], (int)Lo[1], (int)Lo[2], (int)Lo[3]};
        }
    };

    float4 L[4];
    #pragma unroll
    for (int i = 0; i < 4; ++i) L[i] = *reinterpret_cast<const float4*>(gx + i * 4);
    stage(L, 0);
    __syncthreads();

    float msq[4]  = {3.4e38f, 3.4e38f, 3.4e38f, 3.4e38f};
    int   midx[4] = {0, 0, 0, 0};

    for (int c = 0; c < NCHUNK; ++c) {
        const int buf = c & 1;
        if (c + 1 < NCHUNK) {
            const float* g2 = gx + (size_t)(c + 1) * CHUNK * D;
            #pragma unroll
            for (int i = 0; i < 4; ++i) L[i] = *reinterpret_cast<const float4*>(g2 + i * 4);
        }
        f32x4 acc[4][4];
        #pragma unroll
        for (int mi = 0; mi < 4; ++mi)
            #pragma unroll
            for (int ni = 0; ni < 4; ++ni) acc[mi][ni] = f32x4{0.f, 0.f, 0.f, 0.f};

        const int bufo = buf * 32768;
        #pragma unroll
        for (int s = 0; s < 2; ++s) {
            f16x8 ah[4], al[4];
            const int offh = (s * 64) ^ abit6;
            #pragma unroll
            for (int mi = 0; mi < 4; ++mi) {
                ah[mi] = *reinterpret_cast<const f16x8*>(smem + bufo + rowoff[mi] + offh);
                al[mi] = *reinterpret_cast<const f16x8*>(smem + bufo + rowoff[mi] + 128 + offh);
            }
            #pragma unroll
            for (int mi = 0; mi < 4; ++mi)
                #pragma unroll
                for (int ni = 0; ni < 4; ++ni) {
                    acc[mi][ni] = __builtin_amdgcn_mfma_f32_16x16x32_f16(
                        ah[mi], bh[s][ni], acc[mi][ni], 0, 0, 0);
                    acc[mi][ni] = __builtin_amdgcn_mfma_f32_16x16x32_f16(
                        ah[mi], bl[s][ni], acc[mi][ni], 0, 0, 0);
                    acc[mi][ni] = __builtin_amdgcn_mfma_f32_16x16x32_f16(
                        al[mi], bh[s][ni], acc[mi][ni], 0, 0, 0);
                }
        }

        // epilogue: sq = x2 + p2 - 2*dot; strict-< + ascending idx keeps first occurrence
        const float* x2p = reinterpret_cast<const float*>(smem + X2S + buf * 512);
        const int idxb = n0 + c * CHUNK + wr * 64 + hi * 4;
        #pragma unroll
        for (int mi = 0; mi < 4; ++mi) {
            f32x4 xv = *reinterpret_cast<const f32x4*>(x2p + wr * 64 + mi * 16 + hi * 4);
            #pragma unroll
            for (int ni = 0; ni < 4; ++ni) {
                #pragma unroll
                for (int r = 0; r < 4; ++r) {
                    float sq = fmaf(-2.0f, acc[mi][ni][r], xv[r] + p2c[ni]);
                    sq = fmaxf(sq, 0.0f);
                    int idx = idxb + mi * 16 + r;
                    if (sq < msq[ni]) { msq[ni] = sq; midx[ni] = idx; }
                }
            }
        }

        if (c + 1 < NCHUNK) stage(L, buf ^ 1);
        __syncthreads();
    }

    // ---------- reduce: u64 key = (sq_bits<<32)|idx; lower idx wins ties ----------
    u64 key[4];
    #pragma unroll
    for (int ni = 0; ni < 4; ++ni) {
        u64 k = ((u64)__float_as_uint(msq[ni]) << 32) | (u32)midx[ni];
        u64 o = __shfl_xor(k, 16); k = o < k ? o : k;
        o     = __shfl_xor(k, 32); k = o < k ? o : k;
        key[ni] = k;
    }
    u64 k01 = (l & 16) ? key[1] : key[0];
    u64 k23 = (l & 16) ? key[3] : key[2];
    u64 kk  = (l & 32) ? k23 : k01;          // proto_local = wc*64 + l
    u64* xch = reinterpret_cast<u64*>(smem);
    if (wr == 1) xch[wc * 64 + l] = kk;
    __syncthreads();
    if (wr == 0) {
        u64 o = xch[wc * 64 + l];
        kk = o < kk ? o : kk;
        pk[(size_t)ns * (B * P) + (size_t)b * P + pt0 + wc * 64 + l] = kk;
    }
}

__global__ void kfin(const u64* __restrict__ pk, float* __restrict__ out) {
    int i = blockIdx.x * 256 + threadIdx.x;
    if (i >= B * P) return;
    u64 m = pk[i];
    #pragma unroll
    for (int s = 1; s < NSPLIT; ++s) {
        u64 c = pk[(size_t)s * (B * P) + i];
        m = c < m ? c : m;
    }
    float sq = __uint_as_float((u32)(m >> 32));
    out[i] = sqrtf(sq + 1e-8f);                              // prototype_dist
    out[B * P + i] = (float)(u32)(m & 0xFFFFFFFFu);          // patches_idcs (as f32)
}

extern "C" void kernel_launch(void* const* d_in, const int* in_sizes, int n_in,
                              void* d_out, int out_size, void* d_ws, size_t ws_size,
                              hipStream_t stream) {
    const float* x     = (const float*)d_in[0];
    const float* proto = (const float*)d_in[1];
    float* out = (float*)d_out;
    u64* pk = (u64*)d_ws;   // NSPLIT * B * P * 8B = 1 MiB

    kmain<<<dim3(NSPLIT, P / TPB, B), dim3(512), 0, stream>>>(x, proto, pk);
    kfin<<<dim3((B * P + 255) / 256), dim3(256), 0, stream>>>(pk, out);
}

// Round 9
// 105.985 us; speedup vs baseline: 1.3051x; 1.0203x over previous
//
#include <hip/hip_runtime.h>
#include <math.h>

// Problem constants (fixed by the reference setup_inputs).
constexpr int B = 8, N = 16384, P = 512, D = 64;
constexpr int NSPLIT   = 16;              // N-splits (grid.x) -> 256 blocks total
constexpr int ROWS_PB  = N / NSPLIT;      // 1024 rows per block
constexpr int CHUNK    = 128;             // rows per LDS chunk
constexpr int NCHUNK   = ROWS_PB / CHUNK; // 8
constexpr int TPB      = 256;             // protos per block (grid.y = P/TPB = 2)

typedef __attribute__((ext_vector_type(8))) _Float16 f16x8;  // 8 f16 = 4 VGPR
typedef __attribute__((ext_vector_type(4))) float f32x4;
typedef __attribute__((ext_vector_type(4))) int   i32x4;
using u32 = unsigned int;
using u64 = unsigned long long;

// LDS map (bytes):
//   xbuf0 : [0,     32768)   128 rows x 256B (2 f16 planes H|L, XOR-swizzled)
//   xbuf1 : [32768, 65536)
//   x2s   : [65536, 66560)   2 x 128 f32
//   p2s   : [69632, 70656)   256 f32
//   PLO   : [70656, 103424)  256 protos x 128B  B lo-plane (persistent, swizzled)
//   p-temp (phase P only): [0, 69632) = 256 rows x 272B stride (overlaps xbufs+x2s)
constexpr int X2S   = 65536;
constexpr int P2S   = 69632;
constexpr int PLO   = 70656;
constexpr int SMEMB = 103424;   // 1 block/CU

// f32 -> (f16 hi, f16 lo) exact-residual split; pack pairs of values.
__device__ __forceinline__ void cvt2(float a, float b, u32& hw, u32& lw) {
    _Float16 ha = (_Float16)a, hb = (_Float16)b;
    float ra = a - (float)ha, rb = b - (float)hb;     // exact
    _Float16 la = (_Float16)ra, lb = (_Float16)rb;
    hw = (u32)__builtin_bit_cast(unsigned short, ha) |
         ((u32)__builtin_bit_cast(unsigned short, hb) << 16);
    lw = (u32)__builtin_bit_cast(unsigned short, la) |
         ((u32)__builtin_bit_cast(unsigned short, lb) << 16);
}

__global__ __launch_bounds__(1024, 4)   // 16 waves/CU = 4 waves/SIMD, VGPR cap 128
void kmain(const float* __restrict__ x, const float* __restrict__ proto,
           u64* __restrict__ pk) {
    __shared__ __align__(16) char smem[SMEMB];
    const int t  = threadIdx.x;
    const int l  = t & 63;
    const int wv = t >> 6;                   // 16 waves
    const int wr = wv >> 2, wc = wv & 3;     // 4 row-groups x 4 proto-groups
    const int hi = l >> 4, il = l & 15;
    const int ns = blockIdx.x, pt = blockIdx.y, b = blockIdx.z;
    const int n0  = ns * ROWS_PB;
    const int pt0 = pt * TPB;

    // ---------- Phase P: normalize protos; hi plane -> p-temp, lo plane -> PLO ----------
    if (t < TPB) {
        const float4* pr4 = reinterpret_cast<const float4*>(proto + (size_t)(pt0 + t) * D);
        float a0 = 0.f, a1 = 0.f, a2 = 0.f, a3 = 0.f;
        float4 v[16];
        #pragma unroll
        for (int i = 0; i < 16; ++i) {
            v[i] = pr4[i];
            a0 = fmaf(v[i].x, v[i].x, a0);
            a1 = fmaf(v[i].y, v[i].y, a1);
            a2 = fmaf(v[i].z, v[i].z, a2);
            a3 = fmaf(v[i].w, v[i].w, a3);
        }
        float nrm = sqrtf((a0 + a1) + (a2 + a3));
        float sc  = 1.0f / fmaxf(nrm, 1e-12f);
        char* prow = smem + t * 272;            // hi-plane temp row (transient)
        char* plor = smem + PLO + t * 128;      // lo-plane persistent row
        int psw = (t & 7) << 4;                 // lo-plane swizzle (row&7)<<4
        float q0 = 0.f, q1 = 0.f, q2 = 0.f, q3 = 0.f;
        #pragma unroll
        for (int g = 0; g < 8; ++g) {  // 8 k-values per group
            float4 va = v[2 * g], vb = v[2 * g + 1];
            float e[8] = {va.x * sc, va.y * sc, va.z * sc, va.w * sc,
                          vb.x * sc, vb.y * sc, vb.z * sc, vb.w * sc};
            q0 = fmaf(e[0], e[0], fmaf(e[4], e[4], q0));
            q1 = fmaf(e[1], e[1], fmaf(e[5], e[5], q1));
            q2 = fmaf(e[2], e[2], fmaf(e[6], e[6], q2));
            q3 = fmaf(e[3], e[3], fmaf(e[7], e[7], q3));
            u32 H[4], Lo[4];
            #pragma unroll
            for (int jj = 0; jj < 4; ++jj)
                cvt2(e[2 * jj], e[2 * jj + 1], H[jj], Lo[jj]);
            *reinterpret_cast<i32x4*>(prow + g * 16) = i32x4{(int)H[0], (int)H[1], (int)H[2], (int)H[3]};
            *reinterpret_cast<i32x4*>(plor + ((g * 16) ^ psw)) = i32x4{(int)Lo[0], (int)Lo[1], (int)Lo[2], (int)Lo[3]};
        }
        *reinterpret_cast<float*>(smem + P2S + t * 4) = (q0 + q1) + (q2 + q3);
    }
    __syncthreads();

    // ---------- Load B-hi fragments into registers ----------
    // mfma_f32_16x16x32_f16 B layout: lane l -> col = l&15, k = (l>>4)*8 + j
    f16x8 bh[2][4];
    #pragma unroll
    for (int s = 0; s < 2; ++s)
        #pragma unroll
        for (int ni = 0; ni < 4; ++ni) {
            int row = wc * 64 + ni * 16 + il;       // local proto [0,256)
            bh[s][ni] = *reinterpret_cast<const f16x8*>(smem + row * 272 + s * 64 + hi * 16);
        }
    float p2c[4];
    #pragma unroll
    for (int ni = 0; ni < 4; ++ni)
        p2c[ni] = *reinterpret_cast<const float*>(smem + P2S + (wc * 64 + ni * 16 + il) * 4);
    __syncthreads();   // p-temp region now reusable as x buffers

    // per-lane addressing (swizzle: off ^ ((row&7)<<4); row&7 == il&7;
    // bits 4-5 folded into alow, bit 6 applied per-s via abit6)
    const int alow  = (hi * 16) ^ ((il & 3) << 4);
    const int abit6 = (il & 4) << 4;
    const int rowbase = (wr * 32 + il) * 256 + alow;           // A: + mi*4096 (+128 lo)
    const int blbase  = PLO + (wc * 64 + il) * 128 + alow;     // B-lo: + ni*2048

    const float* gx = x + ((size_t)b * N + n0) * D + t * 8;    // row t>>3, octant t&7

    // ---- staging: load 8 f32, split to 2 f16 planes, swizzled ds_write; fold x2 ----
    auto stage = [&](int c, int buf) {
        const float4* src = reinterpret_cast<const float4*>(gx + (size_t)c * CHUNK * D);
        float4 L0 = src[0], L1 = src[1];
        float vals[8] = {L0.x, L0.y, L0.z, L0.w, L1.x, L1.y, L1.z, L1.w};
        float s8 = 0.f;
        #pragma unroll
        for (int i = 0; i < 8; ++i) s8 = fmaf(vals[i], vals[i], s8);
        s8 += __shfl_xor(s8, 1);
        s8 += __shfl_xor(s8, 2);
        s8 += __shfl_xor(s8, 4);
        int row = t >> 3, oct = t & 7;
        if (oct == 0) *reinterpret_cast<float*>(smem + X2S + buf * 512 + row * 4) = s8;
        char* base = smem + buf * 32768 + row * 256;
        int ob = (oct * 16) ^ ((row & 7) << 4);
        u32 H[4], Lo[4];
        #pragma unroll
        for (int jj = 0; jj < 4; ++jj)
            cvt2(vals[2 * jj], vals[2 * jj + 1], H[jj], Lo[jj]);
        *reinterpret_cast<i32x4*>(base +       ob) = i32x4{(int)H[0], (int)H[1], (int)H[2], (int)H[3]};
        *reinterpret_cast<i32x4*>(base + 128 + ob) = i32x4{(int)Lo[0], (int)Lo[1], (int)Lo[2], (int)Lo[3]};
    };

    stage(0, 0);
    __syncthreads();

    float msq[4]  = {3.4e38f, 3.4e38f, 3.4e38f, 3.4e38f};
    int   midx[4] = {0, 0, 0, 0};

    for (int c = 0; c < NCHUNK; ++c) {
        const int buf = c & 1;
        f32x4 acc[2][4];
        #pragma unroll
        for (int mi = 0; mi < 2; ++mi)
            #pragma unroll
            for (int ni = 0; ni < 4; ++ni) acc[mi][ni] = f32x4{0.f, 0.f, 0.f, 0.f};

        const int bufo = buf * 32768;
        #pragma unroll
        for (int s = 0; s < 2; ++s) {
            const int soff = (s * 64) ^ abit6;
            f16x8 ah[2], al[2], blv[4];
            #pragma unroll
            for (int mi = 0; mi < 2; ++mi) {
                ah[mi] = *reinterpret_cast<const f16x8*>(smem + bufo + rowbase + mi * 4096 + soff);
                al[mi] = *reinterpret_cast<const f16x8*>(smem + bufo + rowbase + mi * 4096 + 128 + soff);
            }
            #pragma unroll
            for (int ni = 0; ni < 4; ++ni)
                blv[ni] = *reinterpret_cast<const f16x8*>(smem + blbase + ni * 2048 + soff);
            #pragma unroll
            for (int mi = 0; mi < 2; ++mi)
                #pragma unroll
                for (int ni = 0; ni < 4; ++ni) {
                    acc[mi][ni] = __builtin_amdgcn_mfma_f32_16x16x32_f16(
                        ah[mi], bh[s][ni], acc[mi][ni], 0, 0, 0);
                    acc[mi][ni] = __builtin_amdgcn_mfma_f32_16x16x32_f16(
                        ah[mi], blv[ni], acc[mi][ni], 0, 0, 0);
                    acc[mi][ni] = __builtin_amdgcn_mfma_f32_16x16x32_f16(
                        al[mi], bh[s][ni], acc[mi][ni], 0, 0, 0);
                }
        }

        // epilogue: sq = x2 + p2 - 2*dot; strict-< + ascending idx keeps first occurrence
        const float* x2p = reinterpret_cast<const float*>(smem + X2S + buf * 512);
        const int idxb = n0 + c * CHUNK + wr * 32 + hi * 4;
        #pragma unroll
        for (int mi = 0; mi < 2; ++mi) {
            f32x4 xv = *reinterpret_cast<const f32x4*>(x2p + wr * 32 + mi * 16 + hi * 4);
            #pragma unroll
            for (int ni = 0; ni < 4; ++ni) {
                #pragma unroll
                for (int r = 0; r < 4; ++r) {
                    float sq = fmaf(-2.0f, acc[mi][ni][r], xv[r] + p2c[ni]);
                    sq = fmaxf(sq, 0.0f);
                    int idx = idxb + mi * 16 + r;
                    if (sq < msq[ni]) { msq[ni] = sq; midx[ni] = idx; }
                }
            }
        }

        if (c + 1 < NCHUNK) stage(c + 1, buf ^ 1);
        __syncthreads();
    }

    // ---------- reduce: u64 key = (sq_bits<<32)|idx; lower idx wins ties ----------
    u64 key[4];
    #pragma unroll
    for (int ni = 0; ni < 4; ++ni) {
        u64 k = ((u64)__float_as_uint(msq[ni]) << 32) | (u32)midx[ni];
        u64 o = __shfl_xor(k, 16); k = o < k ? o : k;
        o     = __shfl_xor(k, 32); k = o < k ? o : k;
        key[ni] = k;
    }
    u64* xch = reinterpret_cast<u64*>(smem);
    if (wr > 0 && l < 16) {
        #pragma unroll
        for (int ni = 0; ni < 4; ++ni)
            xch[(wr - 1) * 256 + wc * 64 + ni * 16 + l] = key[ni];
    }
    __syncthreads();
    if (wr == 0 && l < 16) {
        #pragma unroll
        for (int ni = 0; ni < 4; ++ni) {
            u64 kk = key[ni];
            #pragma unroll
            for (int q = 0; q < 3; ++q) {
                u64 o = xch[q * 256 + wc * 64 + ni * 16 + l];
                kk = o < kk ? o : kk;
            }
            pk[(size_t)ns * (B * P) + (size_t)b * P + pt0 + wc * 64 + ni * 16 + l] = kk;
        }
    }
}

__global__ void kfin(const u64* __restrict__ pk, float* __restrict__ out) {
    int i = blockIdx.x * 256 + threadIdx.x;
    if (i >= B * P) return;
    u64 m = pk[i];
    #pragma unroll
    for (int s = 1; s < NSPLIT; ++s) {
        u64 c = pk[(size_t)s * (B * P) + i];
        m = c < m ? c : m;
    }
    float sq = __uint_as_float((u32)(m >> 32));
    out[i] = sqrtf(sq + 1e-8f);                              // prototype_dist
    out[B * P + i] = (float)(u32)(m & 0xFFFFFFFFu);          // patches_idcs (as f32)
}

extern "C" void kernel_launch(void* const* d_in, const int* in_sizes, int n_in,
                              void* d_out, int out_size, void* d_ws, size_t ws_size,
                              hipStream_t stream) {
    const float* x     = (const float*)d_in[0];
    const float* proto = (const float*)d_in[1];
    float* out = (float*)d_out;
    u64* pk = (u64*)d_ws;   // NSPLIT * B * P * 8B = 512 KiB

    kmain<<<dim3(NSPLIT, P / TPB, B), dim3(1024), 0, stream>>>(x, proto, pk);
    kfin<<<dim3((B * P + 255) / 256), dim3(256), 0, stream>>>(pk, out);
}

// Round 12
// 97.962 us; speedup vs baseline: 1.4120x; 1.0819x over previous
//
#include <hip/hip_runtime.h>
#include <math.h>

// Problem constants (fixed by the reference setup_inputs).
constexpr int B = 8, N = 16384, P = 512, D = 64;
constexpr int NSPLIT   = 16;              // grid.x -> 256 blocks total (1/CU)
constexpr int ROWS_PB  = N / NSPLIT;      // 1024 rows per block
constexpr int CHUNK    = 128;             // rows per LDS chunk
constexpr int NCHUNK   = ROWS_PB / CHUNK; // 8
constexpr int TPB      = 256;             // protos per block (grid.y = 2)

typedef __attribute__((ext_vector_type(8))) _Float16 f16x8;  // 8 f16 = 4 VGPR
typedef __attribute__((ext_vector_type(4))) float f32x4;
typedef __attribute__((ext_vector_type(4))) int   i32x4;
using u32 = unsigned int;
using u64 = unsigned long long;

// LDS map (bytes):
//   xbuf0 : [0,      32768)   128 rows x 256B (f16 H|L planes, XOR-swizzled)
//   xbuf1 : [32768,  65536)
//   BREG  : [65536,  131072)  256 protos x 256B (f16 H|L planes, XOR-swizzled)
//   x2s   : [131072, 132096)  2 x 128 f32
//   p2s   : [132096, 133120)  256 f32
constexpr int BREG  = 65536;
constexpr int X2S   = 131072;
constexpr int P2S   = 132096;
constexpr int SMEMB = 133120;   // 130 KiB -> 1 block/CU, 16 waves = 4 waves/SIMD

// f32 -> (f16 hi, f16 lo) exact-residual split; pack pairs of values.
__device__ __forceinline__ void cvt2(float a, float b, u32& hw, u32& lw) {
    _Float16 ha = (_Float16)a, hb = (_Float16)b;
    float ra = a - (float)ha, rb = b - (float)hb;     // exact
    _Float16 la = (_Float16)ra, lb = (_Float16)rb;
    hw = (u32)__builtin_bit_cast(unsigned short, ha) |
         ((u32)__builtin_bit_cast(unsigned short, hb) << 16);
    lw = (u32)__builtin_bit_cast(unsigned short, la) |
         ((u32)__builtin_bit_cast(unsigned short, lb) << 16);
}

__global__ __launch_bounds__(1024, 4)   // 16 waves/block, 1 block/CU, 128-reg cap
void kmain(const float* __restrict__ x, const float* __restrict__ proto,
           u64* __restrict__ pk) {
    __shared__ __align__(16) char smem[SMEMB];
    const int t  = threadIdx.x;
    const int l  = t & 63;
    const int wv = t >> 6;                   // 16 waves
    const int wr = wv >> 2, wc = wv & 3;     // 4 row-groups x 4 proto-groups
    const int hi = l >> 4, il = l & 15;
    const int ns = blockIdx.x, pt = blockIdx.y, b = blockIdx.z;
    const int n0  = ns * ROWS_PB;
    const int pt0 = pt * TPB;

    // ---- issue x chunk-0 loads first (latency hides under phase P) ----
    const float* gxbase = x + ((size_t)b * N + n0) * D;
    const int srow = t >> 3, soct = t & 7;           // staging: row, octant
    float4 A0, A1;
    {
        const float4* src = reinterpret_cast<const float4*>(gxbase) + t * 2;
        A0 = src[0]; A1 = src[1];
    }

    // ---------- Phase P: normalize protos -> BREG (H|L planes, swizzled) ----------
    if (t < TPB) {
        const float4* pr4 = reinterpret_cast<const float4*>(proto + (size_t)(pt0 + t) * D);
        float a0 = 0.f, a1 = 0.f, a2 = 0.f, a3 = 0.f;
        float4 v[16];
        #pragma unroll
        for (int i = 0; i < 16; ++i) {
            v[i] = pr4[i];
            a0 = fmaf(v[i].x, v[i].x, a0);
            a1 = fmaf(v[i].y, v[i].y, a1);
            a2 = fmaf(v[i].z, v[i].z, a2);
            a3 = fmaf(v[i].w, v[i].w, a3);
        }
        float nrm = sqrtf((a0 + a1) + (a2 + a3));
        float sc  = 1.0f / fmaxf(nrm, 1e-12f);
        char* prow = smem + BREG + t * 256;
        int psw = (t & 7) << 4;
        float q0 = 0.f, q1 = 0.f, q2 = 0.f, q3 = 0.f;
        #pragma unroll
        for (int g = 0; g < 8; ++g) {
            float4 va = v[2 * g], vb = v[2 * g + 1];
            float e[8] = {va.x * sc, va.y * sc, va.z * sc, va.w * sc,
                          vb.x * sc, vb.y * sc, vb.z * sc, vb.w * sc};
            q0 = fmaf(e[0], e[0], fmaf(e[4], e[4], q0));
            q1 = fmaf(e[1], e[1], fmaf(e[5], e[5], q1));
            q2 = fmaf(e[2], e[2], fmaf(e[6], e[6], q2));
            q3 = fmaf(e[3], e[3], fmaf(e[7], e[7], q3));
            u32 H[4], Lo[4];
            #pragma unroll
            for (int jj = 0; jj < 4; ++jj)
                cvt2(e[2 * jj], e[2 * jj + 1], H[jj], Lo[jj]);
            int ob = (g * 16) ^ psw;
            *reinterpret_cast<i32x4*>(prow +       ob) = i32x4{(int)H[0], (int)H[1], (int)H[2], (int)H[3]};
            *reinterpret_cast<i32x4*>(prow + 128 + ob) = i32x4{(int)Lo[0], (int)Lo[1], (int)Lo[2], (int)Lo[3]};
        }
        *reinterpret_cast<float*>(smem + P2S + t * 4) = (q0 + q1) + (q2 + q3);
    }

    // ---- stage_write: convert 8 f32 -> H|L planes, swizzled; fold x2 ----
    auto stage_write = [&](float4 L0, float4 L1, int buf) {
        float vals[8] = {L0.x, L0.y, L0.z, L0.w, L1.x, L1.y, L1.z, L1.w};
        float s8 = 0.f;
        #pragma unroll
        for (int i = 0; i < 8; ++i) s8 = fmaf(vals[i], vals[i], s8);
        s8 += __shfl_xor(s8, 1);
        s8 += __shfl_xor(s8, 2);
        s8 += __shfl_xor(s8, 4);
        if (soct == 0) *reinterpret_cast<float*>(smem + X2S + buf * 512 + srow * 4) = s8;
        char* base = smem + buf * 32768 + srow * 256;
        int ob = (soct * 16) ^ ((srow & 7) << 4);
        u32 H[4], Lo[4];
        #pragma unroll
        for (int jj = 0; jj < 4; ++jj)
            cvt2(vals[2 * jj], vals[2 * jj + 1], H[jj], Lo[jj]);
        *reinterpret_cast<i32x4*>(base +       ob) = i32x4{(int)H[0], (int)H[1], (int)H[2], (int)H[3]};
        *reinterpret_cast<i32x4*>(base + 128 + ob) = i32x4{(int)Lo[0], (int)Lo[1], (int)Lo[2], (int)Lo[3]};
    };

    stage_write(A0, A1, 0);
    __syncthreads();   // BREG + xbuf0 + x2s + p2s ready

    // per-lane addressing (swizzle bits 4-5 in alow, bit 6 via abit6 per s)
    const int alow  = (hi * 16) ^ ((il & 3) << 4);
    const int abit6 = (il & 4) << 4;
    int arow[2];
    #pragma unroll
    for (int mi = 0; mi < 2; ++mi)
        arow[mi] = (wr * 32 + mi * 16 + il) * 256 + alow;
    int brow[4];
    #pragma unroll
    for (int ni = 0; ni < 4; ++ni)
        brow[ni] = BREG + (wc * 64 + ni * 16 + il) * 256 + alow;

    // p2 per owned proto column (in-loop comparison must include p2: the
    // reference adds p2 BEFORE the min; deferring it collapses near-ties
    // differently and flips argmins — round-10 lesson).
    float p2c[4];
    #pragma unroll
    for (int ni = 0; ni < 4; ++ni)
        p2c[ni] = *reinterpret_cast<const float*>(
            smem + P2S + (wc * 64 + ni * 16 + il) * 4);

    float msq[4]  = {3.4e38f, 3.4e38f, 3.4e38f, 3.4e38f};
    int   midx[4] = {0, 0, 0, 0};

    for (int c = 0; c < NCHUNK; ++c) {
        const int buf = c & 1;
        const int bufo = buf * 32768;
        f32x4 acc[2][4];
        #pragma unroll
        for (int mi = 0; mi < 2; ++mi)
            #pragma unroll
            for (int ni = 0; ni < 4; ++ni) acc[mi][ni] = f32x4{0.f, 0.f, 0.f, 0.f};

        #pragma unroll
        for (int s = 0; s < 2; ++s) {
            const int soff = (s * 64) ^ abit6;
            f16x8 ah[2], al[2], bh[4], bl[4];
            #pragma unroll
            for (int mi = 0; mi < 2; ++mi) {
                ah[mi] = *reinterpret_cast<const f16x8*>(smem + bufo + arow[mi] + soff);
                al[mi] = *reinterpret_cast<const f16x8*>(smem + bufo + arow[mi] + 128 + soff);
            }
            #pragma unroll
            for (int ni = 0; ni < 4; ++ni)
                bh[ni] = *reinterpret_cast<const f16x8*>(smem + brow[ni] + soff);
            // product-outer: dependent MFMAs on same acc are 8 apart
            #pragma unroll
            for (int ni = 0; ni < 4; ++ni)
                #pragma unroll
                for (int mi = 0; mi < 2; ++mi)
                    acc[mi][ni] = __builtin_amdgcn_mfma_f32_16x16x32_f16(
                        ah[mi], bh[ni], acc[mi][ni], 0, 0, 0);
            #pragma unroll
            for (int ni = 0; ni < 4; ++ni)
                #pragma unroll
                for (int mi = 0; mi < 2; ++mi)
                    acc[mi][ni] = __builtin_amdgcn_mfma_f32_16x16x32_f16(
                        al[mi], bh[ni], acc[mi][ni], 0, 0, 0);
            #pragma unroll
            for (int ni = 0; ni < 4; ++ni)
                bl[ni] = *reinterpret_cast<const f16x8*>(smem + brow[ni] + 128 + soff);
            #pragma unroll
            for (int ni = 0; ni < 4; ++ni)
                #pragma unroll
                for (int mi = 0; mi < 2; ++mi)
                    acc[mi][ni] = __builtin_amdgcn_mfma_f32_16x16x32_f16(
                        ah[mi], bl[ni], acc[mi][ni], 0, 0, 0);
        }

        // issue next chunk's loads: epilogue below covers HBM latency
        if (c + 1 < NCHUNK) {
            const float4* src = reinterpret_cast<const float4*>(
                gxbase + (size_t)(c + 1) * CHUNK * D) + t * 2;
            A0 = src[0]; A1 = src[1];
        }

        // epilogue (round-9 proven semantics): sq = max(fma(-2,dot,x2+p2),0);
        // strict-< + ascending idx keeps first occurrence
        const float* x2p = reinterpret_cast<const float*>(smem + X2S + buf * 512);
        const int idxb = n0 + c * CHUNK + wr * 32 + hi * 4;
        #pragma unroll
        for (int mi = 0; mi < 2; ++mi) {
            f32x4 xv = *reinterpret_cast<const f32x4*>(x2p + wr * 32 + mi * 16 + hi * 4);
            #pragma unroll
            for (int ni = 0; ni < 4; ++ni) {
                #pragma unroll
                for (int r = 0; r < 4; ++r) {
                    float sq = fmaf(-2.0f, acc[mi][ni][r], xv[r] + p2c[ni]);
                    sq = fmaxf(sq, 0.0f);
                    int idx = idxb + mi * 16 + r;
                    if (sq < msq[ni]) { msq[ni] = sq; midx[ni] = idx; }
                }
            }
        }

        if (c + 1 < NCHUNK) stage_write(A0, A1, buf ^ 1);
        __syncthreads();
    }

    // ---------- reduce: u64 key = (sq_bits<<32)|idx; lower idx wins ties ----------
    u64 key[4];
    #pragma unroll
    for (int ni = 0; ni < 4; ++ni) {
        u64 k = ((u64)__float_as_uint(msq[ni]) << 32) | (u32)midx[ni];
        u64 o = __shfl_xor(k, 16); k = o < k ? o : k;
        o     = __shfl_xor(k, 32); k = o < k ? o : k;
        key[ni] = k;
    }
    u64* xch = reinterpret_cast<u64*>(smem);
    if (wr > 0 && l < 16) {
        #pragma unroll
        for (int ni = 0; ni < 4; ++ni)
            xch[(wr - 1) * 256 + wc * 64 + ni * 16 + l] = key[ni];
    }
    __syncthreads();
    if (wr == 0 && l < 16) {
        #pragma unroll
        for (int ni = 0; ni < 4; ++ni) {
            u64 kk = key[ni];
            #pragma unroll
            for (int q = 0; q < 3; ++q) {
                u64 o = xch[q * 256 + wc * 64 + ni * 16 + l];
                kk = o < kk ? o : kk;
            }
            pk[(size_t)ns * (B * P) + (size_t)b * P + pt0 + wc * 64 + ni * 16 + l] = kk;
        }
    }
}

__global__ void kfin(const u64* __restrict__ pk, float* __restrict__ out) {
    int i = blockIdx.x * 256 + threadIdx.x;
    if (i >= B * P) return;
    u64 m = pk[i];
    #pragma unroll
    for (int s = 1; s < NSPLIT; ++s) {
        u64 c = pk[(size_t)s * (B * P) + i];
        m = c < m ? c : m;
    }
    float sq = __uint_as_float((u32)(m >> 32));
    out[i] = sqrtf(sq + 1e-8f);                              // prototype_dist
    out[B * P + i] = (float)(u32)(m & 0xFFFFFFFFu);          // patches_idcs (as f32)
}

extern "C" void kernel_launch(void* const* d_in, const int* in_sizes, int n_in,
                              void* d_out, int out_size, void* d_ws, size_t ws_size,
                              hipStream_t stream) {
    const float* x     = (const float*)d_in[0];
    const float* proto = (const float*)d_in[1];
    float* out = (float*)d_out;
    u64* pk = (u64*)d_ws;   // NSPLIT * B * P * 8B = 512 KiB

    kmain<<<dim3(NSPLIT, P / TPB, B), dim3(1024), 0, stream>>>(x, proto, pk);
    kfin<<<dim3((B * P + 255) / 256), dim3(256), 0, stream>>>(pk, out);
}